// Round 7
// baseline (367.060 us; speedup 1.0000x reference)
//
#include <hip/hip_runtime.h>
#include <math.h>

// Sizes (fixed by the problem)
#define B_SZ 8
#define L_SZ 4096
#define D_SZ 1024
#define M_SZ 64
#define ROWS (B_SZ * L_SZ)   // 32768
#define NCHUNK 64            // L / CHUNK
#define CHUNK 64

#define FMA4(acc, sc, v) { (acc).x += (sc)*(v).x; (acc).y += (sc)*(v).y; (acc).z += (sc)*(v).z; (acc).w += (sc)*(v).w; }
#define SCALE4(v, sc) { (v).x *= (sc); (v).y *= (sc); (v).z *= (sc); (v).w *= (sc); }

typedef __attribute__((ext_vector_type(8))) short bf16x8;
typedef __attribute__((ext_vector_type(4))) float f32x4;

__device__ __forceinline__ float sigmoid_f(float z) { return 1.0f / (1.0f + __expf(-z)); }
__device__ __forceinline__ float decay_of(const float* __restrict__ dp) {
  return 0.9f + (0.999f - 0.9f) * sigmoid_f(dp[0]);
}
// fp32 -> bf16 round-to-nearest-even
__device__ __forceinline__ unsigned short f2bf(float f) {
  unsigned int u = __float_as_uint(f);
  unsigned int r = (u + 0x7FFFu + ((u >> 16) & 1u)) >> 16;
  return (unsigned short)r;
}

// async global->LDS, 16B per lane. HW: wave-uniform LDS base + lane*16;
// per-lane GLOBAL source. All call sites keep waves fully active.
__device__ __forceinline__ void gl2lds16(const void* g, void* l) {
  __builtin_amdgcn_global_load_lds(
      (const __attribute__((address_space(1))) unsigned int*)g,
      (__attribute__((address_space(3))) unsigned int*)l, 16, 0, 0);
}

// ---------------- Kernel 0: qkv weight prep ----------------
// Wt in k1's staged order: [kt 0..15][n 0..207][chunk 0..8][8 bf16], each
// kt-slice padded to 2048 16B-chunks (32768B) -> B-stage = exactly 4
// chunks/thread at 512 threads (uniform per-wave vmcnt accounting).
// n: 0-63 Wq cols, 64-127 Wk, 128-191 Wv, 192 Wg, 193-207 zero. chunk 8 = row pad.
// Chunks 1872..2047: dead pad, staged into an LDS region compute never reads.
#define BT_CH_PAD 2048
#define BT_BYTES  (BT_CH_PAD * 16)
__global__ __launch_bounds__(256) void k0_prep(
    const float* __restrict__ Wq, const float* __restrict__ Wk,
    const float* __restrict__ Wv, const float* __restrict__ Wg,
    unsigned short* __restrict__ Wt)
{
  const int n = blockIdx.x;      // 0..207
  #pragma unroll
  for (int j = 0; j < 5; ++j) {
    int idx = threadIdx.x + 256 * j;   // 0..1151 : 16 kt * 72 shorts
    if (idx < 1152) {
      int kt = idx / 72;
      int r  = idx - kt * 72;
      int c = r >> 3, e = r & 7;
      float v = 0.f;
      if (c < 8 && n < 193) {
        int k = kt * 64 + c * 8 + e;
        v = (n < 64)  ? Wq[(size_t)k * 64 + n]
          : (n < 128) ? Wk[(size_t)k * 64 + (n - 64)]
          : (n < 192) ? Wv[(size_t)k * 64 + (n - 128)]
                      : Wg[k];
      }
      Wt[((size_t)kt * BT_CH_PAD + (size_t)n * 9 + c) * 8 + e] = f2bf(v);
    }
  }
}

// ---------------- Kernel 1: MFMA fused q,k,v,gate projection ----------------
// v5 (depth-2 counted pipeline; R6 resubmit, audited): 128-row blocks,
// 512 threads (8 waves), grid 256 = 1 block/CU, 128KB LDS.
//  - BOTH A (x, HBM) and B (weights, L2) double-buffered; tiles t and t+1 in
//    flight (8 VMEM ops/thread/tile). Loop waits s_waitcnt vmcnt(8): tile t
//    landed, tile t+1 stays in flight across BOTH barriers -> B latency
//    hidden under compute (R5 exposed it every iteration).
//  - B-traffic halves vs R5: 512KB Wt amortized over 128 rows -> 134MB total.
//  - A rows unpadded (256B); XOR swizzle byte^=(row&7)<<4 applied to the
//    global SOURCE and the LDS frag READ (both-sides involution, rule #21).
//  - Gate = 13th N-tile; epilogue LDS-transpose -> coalesced float4 stores.
#define K1_ROWS 128
#define B_STRIDE 144          // 64 bf16 + 16B pad

__global__ __launch_bounds__(512, 2) void k1_qkvg_mfma(
    const float* __restrict__ x, const unsigned short* __restrict__ Wt,
    const float* __restrict__ bg,
    float* __restrict__ q_ws, float* __restrict__ a_ws, float* __restrict__ b_ws)
{
  __shared__ __align__(16) unsigned char As[2][32768];   // 2 x 128 rows x 256B
  __shared__ __align__(16) unsigned char Bs[2][BT_BYTES];// 2 x 32768B

  const int tid  = threadIdx.x;
  const int lane = tid & 63;
  const int w    = tid >> 6;        // wave 0..7 -> rows 16w..16w+15
  const int quad = lane >> 4;
  const int l15  = lane & 15;
  const int row0 = blockIdx.x * K1_ROWS;

  const unsigned char* xb  = (const unsigned char*)(x + (size_t)row0 * D_SZ);
  const unsigned char* wtb = (const unsigned char*)Wt;

  // Per-thread A staging: 4 chunks, XOR-swizzled global source.
  // chunk c = i*512+tid -> row = c>>4 (0..127), c16 = c&15;
  // src col byte = (c16*16) ^ ((row&7)<<4)  (involution; 16B-aligned).
  const unsigned char* xAsrc[4];
  #pragma unroll
  for (int i = 0; i < 4; ++i) {
    int c   = i * 512 + tid;
    int row = c >> 4, c16 = c & 15;
    xAsrc[i] = xb + (size_t)row * 4096 + ((c16 * 16) ^ ((row & 7) << 4));
  }

  f32x4 acc[13];
  #pragma unroll
  for (int tn = 0; tn < 13; ++tn) acc[tn] = (f32x4){0.f, 0.f, 0.f, 0.f};

  const int arow = 16 * w + l15;
  const int sw   = (l15 & 7) << 4;

  // ---- staging: one tile = A(4 ops) + B(4 ops) per thread, uniform ----
  auto stageAB = [&](int t) {
    const int buf = t & 1;
    #pragma unroll
    for (int i = 0; i < 4; ++i)
      gl2lds16(xAsrc[i] + (size_t)t * 256, As[buf] + (i * 512 + tid) * 16);
    const unsigned char* wt_t = wtb + (size_t)t * BT_BYTES;
    #pragma unroll
    for (int i = 0; i < 4; ++i)
      gl2lds16(wt_t + (i * 512 + tid) * 16, Bs[buf] + (i * 512 + tid) * 16);
  };
  auto compute = [&](int buf) {
    bf16x8 af[2];
    const unsigned char* ap = As[buf] + arow * 256;
    #pragma unroll
    for (int kt = 0; kt < 2; ++kt) {
      float4 lo = *reinterpret_cast<const float4*>(ap + ((kt * 128 + quad * 32) ^ sw));
      float4 hi = *reinterpret_cast<const float4*>(ap + ((kt * 128 + quad * 32 + 16) ^ sw));
      uint4 p;
      p.x = (unsigned)f2bf(lo.x) | ((unsigned)f2bf(lo.y) << 16);
      p.y = (unsigned)f2bf(lo.z) | ((unsigned)f2bf(lo.w) << 16);
      p.z = (unsigned)f2bf(hi.x) | ((unsigned)f2bf(hi.y) << 16);
      p.w = (unsigned)f2bf(hi.z) | ((unsigned)f2bf(hi.w) << 16);
      af[kt] = *reinterpret_cast<bf16x8*>(&p);
    }
    #pragma unroll
    for (int tn = 0; tn < 13; ++tn) {
      #pragma unroll
      for (int kt = 0; kt < 2; ++kt) {
        bf16x8 bf = *reinterpret_cast<const bf16x8*>(
            Bs[buf] + (tn * 16 + l15) * B_STRIDE + kt * 64 + quad * 16);
        acc[tn] = __builtin_amdgcn_mfma_f32_16x16x32_bf16(af[kt], bf, acc[tn], 0, 0, 0);
      }
    }
  };

  // ---- depth-2 pipeline ----
  // Invariant at top of iter t: outstanding VMEM/thread = [tile t: 8, tile t+1: 8].
  stageAB(0);
  stageAB(1);
  for (int t = 0; t < 15; ++t) {
    asm volatile("s_waitcnt vmcnt(8)" ::: "memory");   // tile t landed (mine)
    __builtin_amdgcn_sched_barrier(0);
    __builtin_amdgcn_s_barrier();                      // landed for ALL waves
    compute(t & 1);
    asm volatile("s_waitcnt lgkmcnt(0)" ::: "memory"); // my LDS reads complete
    __builtin_amdgcn_sched_barrier(0);
    __builtin_amdgcn_s_barrier();                      // safe to overwrite buf
    if (t < 14) stageAB(t + 2);                        // refill: +8 in flight
  }
  // t = 15
  asm volatile("s_waitcnt vmcnt(0)" ::: "memory");
  __builtin_amdgcn_sched_barrier(0);
  __builtin_amdgcn_s_barrier();
  compute(1);
  __syncthreads();   // full drain before T aliases As

  // ---- gate: col 192 lives at l15==0 lanes of acc[12]; broadcast per quad ----
  const float bg0 = bg[0];
  float g4[4];
  #pragma unroll
  for (int r = 0; r < 4; ++r) {
    float gv = __shfl(acc[12][r], lane & 48);
    g4[r] = sigmoid_f(gv + bg0);
  }

  // ---- epilogue: transpose via LDS, coalesced float4 stores ----
  float (*T)[68] = (float(*)[68])As;   // 128*68*4 = 34816 <= 65536
  const int erow = tid >> 2, eq4 = tid & 3;
  #pragma unroll
  for (int p = 0; p < 3; ++p) {
    float* dst = (p == 0) ? q_ws : (p == 1) ? a_ws : b_ws;
    #pragma unroll
    for (int tn4 = 0; tn4 < 4; ++tn4) {
      #pragma unroll
      for (int r = 0; r < 4; ++r) {
        float v = acc[p * 4 + tn4][r];
        if (p > 0) v *= g4[r];
        T[16 * w + quad * 4 + r][tn4 * 16 + l15] = v;
      }
    }
    __syncthreads();
    float4 vv[4];
    #pragma unroll
    for (int j = 0; j < 4; ++j)
      vv[j] = *reinterpret_cast<float4*>(&T[erow][eq4 * 16 + 4 * j]);
    #pragma unroll
    for (int j = 0; j < 4; ++j)
      *reinterpret_cast<float4*>(&dst[(size_t)(row0 + erow) * 64 + eq4 * 16 + 4 * j]) = vv[j];
    if (p < 2) __syncthreads();
  }
}

// ---------------- Kernel 2: per-chunk state delta ----------------
__global__ __launch_bounds__(256) void k2_delta(
    const float* __restrict__ a_ws, const float* __restrict__ b_ws,
    const float* __restrict__ dp, float* __restrict__ dS)
{
  __shared__ float Aa[64][64];
  __shared__ float Bc[64][64];
  __shared__ float pw[64];
  const int tid = threadIdx.x;
  const int bc = blockIdx.x;
  const int rowbase = (bc >> 6) * L_SZ + (bc & 63) * CHUNK;
  const int s = tid >> 2, m0 = (tid & 3) * 16;
  #pragma unroll
  for (int j = 0; j < 4; ++j) {
    *reinterpret_cast<float4*>(&Aa[s][m0 + 4*j]) =
        *reinterpret_cast<const float4*>(&a_ws[(size_t)(rowbase + s) * 64 + m0 + 4*j]);
    *reinterpret_cast<float4*>(&Bc[s][m0 + 4*j]) =
        *reinterpret_cast<const float4*>(&b_ws[(size_t)(rowbase + s) * 64 + m0 + 4*j]);
  }
  if (tid < 64) pw[tid] = powf(decay_of(dp), (float)(63 - tid));
  __syncthreads();
  const int d0 = tid >> 2, e0 = (tid & 3) * 16;
  float4 o0 = make_float4(0,0,0,0), o1 = o0, o2 = o0, o3 = o0;
  for (int ss = 0; ss < 64; ++ss) {
    float wa = pw[ss] * Aa[ss][d0];
    float4 b0 = *reinterpret_cast<float4*>(&Bc[ss][e0+0]);
    float4 b1 = *reinterpret_cast<float4*>(&Bc[ss][e0+4]);
    float4 b2 = *reinterpret_cast<float4*>(&Bc[ss][e0+8]);
    float4 b3 = *reinterpret_cast<float4*>(&Bc[ss][e0+12]);
    FMA4(o0, wa, b0); FMA4(o1, wa, b1); FMA4(o2, wa, b2); FMA4(o3, wa, b3);
  }
  float* dst = &dS[((size_t)bc << 12) + d0 * 64 + e0];
  *reinterpret_cast<float4*>(dst + 0)  = o0;
  *reinterpret_cast<float4*>(dst + 4)  = o1;
  *reinterpret_cast<float4*>(dst + 8)  = o2;
  *reinterpret_cast<float4*>(dst + 12) = o3;
}

// ---------------- Kernel 3: elementwise scan over chunks ----------------
__global__ __launch_bounds__(256) void k3_scan(
    const float* __restrict__ dS, const float* __restrict__ dp,
    float* __restrict__ Sst, float* __restrict__ sfin)
{
  const int g = blockIdx.x * 256 + threadIdx.x;
  const int b = g >> 12;
  const int de = g & 4095;
  const float dC = powf(decay_of(dp), 64.0f);
  const size_t base = ((size_t)(b * 64) << 12) + de;
  float d[NCHUNK];
  #pragma unroll
  for (int c = 0; c < NCHUNK; ++c) d[c] = dS[base + ((size_t)c << 12)];
  float s = 0.f;
  #pragma unroll
  for (int c = 0; c < NCHUNK; ++c) {
    Sst[base + ((size_t)c << 12)] = s;
    s = dC * s + d[c];
  }
  sfin[((size_t)b << 12) + de] = s;
}

// ---------------- Kernel 4: intra-chunk outputs ----------------
__global__ __launch_bounds__(256) void k4_intra(
    const float* __restrict__ q_ws, const float* __restrict__ a_ws,
    const float* __restrict__ b_ws, const float* __restrict__ Sst,
    const float* __restrict__ dp, float* __restrict__ outs)
{
  __shared__ float Qs[64][68];
  __shared__ float Ps[64][68];
  __shared__ float Bs[64][64];
  __shared__ float S0s[64][64];
  __shared__ float pw[65];
  const int tid = threadIdx.x;
  const int bc = blockIdx.x;
  const int rowbase = (bc >> 6) * L_SZ + (bc & 63) * CHUNK;
  const int s = tid >> 2, m0 = (tid & 3) * 16;
  #pragma unroll
  for (int j = 0; j < 4; ++j) {
    float4 qv = *reinterpret_cast<const float4*>(&q_ws[(size_t)(rowbase + s) * 64 + m0 + 4*j]);
    Qs[s][m0+4*j+0] = qv.x; Qs[s][m0+4*j+1] = qv.y; Qs[s][m0+4*j+2] = qv.z; Qs[s][m0+4*j+3] = qv.w;
    float4 av = *reinterpret_cast<const float4*>(&a_ws[(size_t)(rowbase + s) * 64 + m0 + 4*j]);
    Ps[m0+4*j+0][s] = av.x; Ps[m0+4*j+1][s] = av.y; Ps[m0+4*j+2][s] = av.z; Ps[m0+4*j+3][s] = av.w;
    float4 bv = *reinterpret_cast<const float4*>(&b_ws[(size_t)(rowbase + s) * 64 + m0 + 4*j]);
    *reinterpret_cast<float4*>(&Bs[s][m0+4*j]) = bv;
    float4 sv = *reinterpret_cast<const float4*>(&Sst[((size_t)bc << 12) + tid*16 + 4*j]);
    *reinterpret_cast<float4*>(&(&S0s[0][0])[tid*16 + 4*j]) = sv;
  }
  if (tid < 65) pw[tid] = powf(decay_of(dp), (float)tid);
  __syncthreads();

  const int t0 = tid >> 2, c0 = (tid & 3) * 16;
  float4 r0 = make_float4(0,0,0,0), r1 = r0, r2 = r0, r3 = r0;
  for (int m = 0; m < 64; ++m) {
    float qv = Qs[t0][m];
    float4 a0 = *reinterpret_cast<float4*>(&Ps[m][c0+0]);
    float4 a1 = *reinterpret_cast<float4*>(&Ps[m][c0+4]);
    float4 a2 = *reinterpret_cast<float4*>(&Ps[m][c0+8]);
    float4 a3 = *reinterpret_cast<float4*>(&Ps[m][c0+12]);
    FMA4(r0, qv, a0); FMA4(r1, qv, a1); FMA4(r2, qv, a2); FMA4(r3, qv, a3);
  }
  float rr[16] = {r0.x,r0.y,r0.z,r0.w, r1.x,r1.y,r1.z,r1.w,
                  r2.x,r2.y,r2.z,r2.w, r3.x,r3.y,r3.z,r3.w};
  __syncthreads();
  #pragma unroll
  for (int j = 0; j < 16; ++j) {
    const int sidx = c0 + j;
    Ps[t0][sidx] = (sidx <= t0) ? rr[j] * pw[t0 - sidx] : 0.f;
  }
  __syncthreads();

  float4 o0 = make_float4(0,0,0,0), o1 = o0, o2 = o0, o3 = o0;
  for (int m = 0; m < 64; ++m) {
    float qv = Qs[t0][m];
    float4 v0 = *reinterpret_cast<float4*>(&S0s[m][c0+0]);
    float4 v1 = *reinterpret_cast<float4*>(&S0s[m][c0+4]);
    float4 v2 = *reinterpret_cast<float4*>(&S0s[m][c0+8]);
    float4 v3 = *reinterpret_cast<float4*>(&S0s[m][c0+12]);
    FMA4(o0, qv, v0); FMA4(o1, qv, v1); FMA4(o2, qv, v2); FMA4(o3, qv, v3);
  }
  const float dsc = pw[t0 + 1];
  SCALE4(o0, dsc); SCALE4(o1, dsc); SCALE4(o2, dsc); SCALE4(o3, dsc);
  for (int ss = 0; ss < 64; ++ss) {
    float pv = Ps[t0][ss];
    float4 b0 = *reinterpret_cast<float4*>(&Bs[ss][c0+0]);
    float4 b1 = *reinterpret_cast<float4*>(&Bs[ss][c0+4]);
    float4 b2 = *reinterpret_cast<float4*>(&Bs[ss][c0+8]);
    float4 b3 = *reinterpret_cast<float4*>(&Bs[ss][c0+12]);
    FMA4(o0, pv, b0); FMA4(o1, pv, b1); FMA4(o2, pv, b2); FMA4(o3, pv, b3);
  }
  float* dst = &outs[(size_t)(rowbase + t0) * 64 + c0];
  *reinterpret_cast<float4*>(dst + 0)  = o0;
  *reinterpret_cast<float4*>(dst + 4)  = o1;
  *reinterpret_cast<float4*>(dst + 8)  = o2;
  *reinterpret_cast<float4*>(dst + 12) = o3;
}

// ---------------- Kernel 5: output projection (scalar) ----------------
// Os stride 65 (== 1 mod 32) de-aliases the scalar a-reads.
__global__ __launch_bounds__(256) void k5_proj(
    const float* __restrict__ outs, const float* __restrict__ Wo,
    const float* __restrict__ bo, float* __restrict__ y)
{
  __shared__ float Os[64][65];
  __shared__ float Ws[64][64];
  const int tid = threadIdx.x;
  const int tx = tid & 15, ty = tid >> 4;
  const int row0 = blockIdx.x * 64;
  const int n0 = blockIdx.y * 64;
  const int s = tid >> 2, m0 = (tid & 3) * 16;
  #pragma unroll
  for (int j = 0; j < 4; ++j) {
    float4 ov = *reinterpret_cast<const float4*>(&outs[(size_t)(row0 + s) * 64 + m0 + 4*j]);
    Os[s][m0+4*j+0] = ov.x; Os[s][m0+4*j+1] = ov.y; Os[s][m0+4*j+2] = ov.z; Os[s][m0+4*j+3] = ov.w;
    float4 wv = *reinterpret_cast<const float4*>(&Wo[(size_t)s * D_SZ + n0 + m0 + 4*j]);
    *reinterpret_cast<float4*>(&Ws[s][m0+4*j]) = wv;
  }
  __syncthreads();
  float4 acc[4];
  #pragma unroll
  for (int r = 0; r < 4; ++r) acc[r] = make_float4(0,0,0,0);
  for (int kk = 0; kk < 64; ++kk) {
    float a0 = Os[4*ty+0][kk];
    float a1 = Os[4*ty+1][kk];
    float a2 = Os[4*ty+2][kk];
    float a3 = Os[4*ty+3][kk];
    float4 w = *reinterpret_cast<float4*>(&Ws[kk][4*tx]);
    FMA4(acc[0], a0, w); FMA4(acc[1], a1, w); FMA4(acc[2], a2, w); FMA4(acc[3], a3, w);
  }
  float4 bv = *reinterpret_cast<const float4*>(&bo[n0 + 4*tx]);
  #pragma unroll
  for (int r = 0; r < 4; ++r) {
    float4 res;
    res.x = acc[r].x + bv.x; res.y = acc[r].y + bv.y;
    res.z = acc[r].z + bv.z; res.w = acc[r].w + bv.w;
    *reinterpret_cast<float4*>(&y[(size_t)(row0 + 4*ty + r) * D_SZ + n0 + 4*tx]) = res;
  }
}

// ---------------- Launcher ----------------
extern "C" void kernel_launch(void* const* d_in, const int* in_sizes, int n_in,
                              void* d_out, int out_size, void* d_ws, size_t ws_size,
                              hipStream_t stream) {
  (void)in_sizes; (void)n_in; (void)out_size; (void)ws_size;
  const float* x  = (const float*)d_in[0];
  const float* Wq = (const float*)d_in[1];
  const float* Wk = (const float*)d_in[2];
  const float* Wv = (const float*)d_in[3];
  const float* Wo = (const float*)d_in[4];
  const float* bo = (const float*)d_in[5];
  const float* Wg = (const float*)d_in[6];
  const float* bg = (const float*)d_in[7];
  const float* dp = (const float*)d_in[8];

  float* y    = (float*)d_out;                       // (8,4096,1024)
  float* sfin = y + (size_t)B_SZ * L_SZ * D_SZ;      // (8,64,64)

  float* ws   = (float*)d_ws;
  const size_t SEG = (size_t)ROWS * M_SZ;            // 2,097,152 floats
  float* q_ws = ws;
  float* a_ws = q_ws + SEG;
  float* b_ws = a_ws + SEG;
  float* dS   = b_ws + SEG;   // (B*NC, 64,64)
  float* Sst  = dS   + SEG;   // chunk-start states
  float* outs = Sst  + SEG;   // (32768, 64)
  // Wt (bf16, 16 slices x 32768B = 512KB) aliases the head of `outs`: dead
  // after k1 reads it, before k4 writes outs. Rewritten every call.
  unsigned short* Wt = (unsigned short*)outs;

  k0_prep<<<dim3(208), dim3(256), 0, stream>>>(Wq, Wk, Wv, Wg, Wt);
  k1_qkvg_mfma<<<dim3(ROWS / K1_ROWS), dim3(512), 0, stream>>>(x, Wt, bg, q_ws, a_ws, b_ws);
  k2_delta<<<dim3(B_SZ * NCHUNK), dim3(256), 0, stream>>>(a_ws, b_ws, dp, dS);
  k3_scan<<<dim3((B_SZ * M_SZ * M_SZ) / 256), dim3(256), 0, stream>>>(dS, dp, Sst, sfin);
  k4_intra<<<dim3(B_SZ * NCHUNK), dim3(256), 0, stream>>>(q_ws, a_ws, b_ws, Sst, dp, outs);
  k5_proj<<<dim3(ROWS / 64, D_SZ / 64), dim3(256), 0, stream>>>(outs, Wo, bo, y);
}